// Round 3
// baseline (231.590 us; speedup 1.0000x reference)
//
#include <hip/hip_runtime.h>
#include <hip/hip_cooperative_groups.h>

namespace cg = cooperative_groups;

#define Bsz  256
#define Pn   2048
#define En   16
#define HIDn 128
#define OUTn 128
#define BN_EPS 1e-5f

struct Params {
    const float *pts0, *pts1;
    const int   *cnt0, *cnt1;
    const float *c0, *ls0, *c1, *ls1;
    const float *W1, *g1, *be1, *W2, *g2, *be2;
    float *out;
    float *u, *ypre, *m1, *r1, *m2, *r2;
};

// One cooperative kernel: SLayer -> W1 -> BN1+ReLU -> W2 -> BN2 -> L2norm.
// grid = 256 blocks (1/CU) x 512 threads. 4 grid syncs.
__global__ __launch_bounds__(512) void fused(Params P)
{
    cg::grid_group grid = cg::this_grid();

    __shared__ float cst[2][En][5];   // quadratic-form consts per (dim,center)
    __shared__ float red[8][32];      // cross-wave scratch
    __shared__ float row[128];        // xrow (32) then hrow (128)

    const int tid = threadIdx.x;
    const int b   = blockIdx.x;

    // ---- precompute per-center constants (ln2-folded quadratic form) ----
    // resp = exp(-(s0 dx^2 + s1 dy^2)) = exp2(ax*x^2 + bx*x + ay*y^2 + by*y + g)
    if (tid < 32) {
        int h = tid >> 4, e = tid & 15;
        const float* C = h ? P.c1 : P.c0;
        const float* L = h ? P.ls1 : P.ls0;
        float cx = C[e * 2 + 0], cy = C[e * 2 + 1];
        float z0 = L[e * 2 + 0], z1 = L[e * 2 + 1];
        float s0 = ((z0 > 20.f) ? z0 : logf(1.f + expf(z0))) + 1e-6f;
        float s1 = ((z1 > 20.f) ? z1 : logf(1.f + expf(z1))) + 1e-6f;
        const float L2E = 1.44269504088896340736f;
        float q0 = s0 * L2E, q1 = s1 * L2E;
        cst[h][e][0] = -q0;
        cst[h][e][1] = 2.f * q0 * cx;
        cst[h][e][2] = -q1;
        cst[h][e][3] = 2.f * q1 * cy;
        cst[h][e][4] = -(q0 * cx * cx + q1 * cy * cy);
    }
    __syncthreads();

    // ---- Phase A: SLayer, both homology dims, masked full scan ----
    float acc[32];
    #pragma unroll
    for (int i = 0; i < 32; i++) acc[i] = 0.f;

    const int n0 = P.cnt0[b];
    const int n1 = P.cnt1[b];
    const float2* p0 = (const float2*)P.pts0 + (size_t)b * Pn;
    const float2* p1 = (const float2*)P.pts1 + (size_t)b * Pn;

    #pragma unroll
    for (int k = 0; k < 4; k++) {
        const int p = tid + k * 512;
        float2 a = p0[p];
        float2 c = p1[p];
        // mask: x -> 1e18 makes ax*x^2 <= -1e30 -> exp2 -> exactly 0
        float ax = (p < n0) ? a.x : 1e18f;
        float ay = (p < n0) ? a.y : 0.f;
        float cx = (p < n1) ? c.x : 1e18f;
        float cy = (p < n1) ? c.y : 0.f;
        float ax2 = ax * ax, ay2 = ay * ay;
        float cx2 = cx * cx, cy2 = cy * cy;
        #pragma unroll
        for (int e = 0; e < En; e++) {
            float t = cst[0][e][4];
            t = fmaf(cst[0][e][0], ax2, t);
            t = fmaf(cst[0][e][1], ax,  t);
            t = fmaf(cst[0][e][2], ay2, t);
            t = fmaf(cst[0][e][3], ay,  t);
            acc[e] += exp2f(t);
            float s = cst[1][e][4];
            s = fmaf(cst[1][e][0], cx2, s);
            s = fmaf(cst[1][e][1], cx,  s);
            s = fmaf(cst[1][e][2], cy2, s);
            s = fmaf(cst[1][e][3], cy,  s);
            acc[16 + e] += exp2f(s);
        }
    }

    // intra-wave butterfly, then cross-wave via LDS
    #pragma unroll
    for (int i = 0; i < 32; i++) {
        float v = acc[i];
        #pragma unroll
        for (int off = 32; off > 0; off >>= 1) v += __shfl_down(v, off, 64);
        acc[i] = v;
    }
    const int wave = tid >> 6, lane = tid & 63;
    if (lane == 0) {
        #pragma unroll
        for (int i = 0; i < 32; i++) red[wave][i] = acc[i];
    }
    __syncthreads();
    if (tid < 32) {
        float s = 0.f;
        #pragma unroll
        for (int w = 0; w < 8; w++) s += red[w][tid];
        row[tid] = s;
    }
    __syncthreads();

    // ---- x @ W1 -> u_reg (thread tid<128 owns u[b][tid]) ----
    float u_reg = 0.f;
    if (tid < HIDn) {
        #pragma unroll
        for (int k = 0; k < 32; k++) u_reg = fmaf(row[k], P.W1[k * HIDn + tid], u_reg);
        P.u[b * HIDn + tid] = u_reg;
    }
    grid.sync();

    // ---- Phase B: BN1 stats — block j<128 reduces column j of u ----
    {
        float s = 0.f, q = 0.f;
        if (b < HIDn && tid < Bsz) {
            float x = P.u[tid * HIDn + b];
            s = x; q = x * x;
        }
        #pragma unroll
        for (int off = 32; off > 0; off >>= 1) {
            s += __shfl_down(s, off, 64);
            q += __shfl_down(q, off, 64);
        }
        if (lane == 0) { red[wave][0] = s; red[wave][1] = q; }
        __syncthreads();
        if (b < HIDn && tid == 0) {
            float S = red[0][0] + red[1][0] + red[2][0] + red[3][0];
            float Q = red[0][1] + red[1][1] + red[2][1] + red[3][1];
            float m = S * (1.f / Bsz);
            float var = Q * (1.f / Bsz) - m * m;
            P.m1[b] = m;
            P.r1[b] = rsqrtf(var + BN_EPS);
        }
    }
    grid.sync();

    // ---- Phase C: BN1 + ReLU + h @ W2 -> yp_reg ----
    float yp_reg = 0.f;
    if (tid < HIDn) {
        float m = P.m1[tid], r = P.r1[tid];
        float h = fmaxf(fmaf((u_reg - m) * r, P.g1[tid], P.be1[tid]), 0.f);
        row[tid] = h;
    }
    __syncthreads();
    if (tid < HIDn) {
        #pragma unroll 8
        for (int k = 0; k < HIDn; k++) yp_reg = fmaf(row[k], P.W2[k * OUTn + tid], yp_reg);
        P.ypre[b * OUTn + tid] = yp_reg;
    }
    grid.sync();

    // ---- Phase D: BN2 stats — block j<128 reduces column j of ypre ----
    {
        float s = 0.f, q = 0.f;
        if (b < OUTn && tid < Bsz) {
            float x = P.ypre[tid * OUTn + b];
            s = x; q = x * x;
        }
        #pragma unroll
        for (int off = 32; off > 0; off >>= 1) {
            s += __shfl_down(s, off, 64);
            q += __shfl_down(q, off, 64);
        }
        if (lane == 0) { red[wave][0] = s; red[wave][1] = q; }
        __syncthreads();
        if (b < OUTn && tid == 0) {
            float S = red[0][0] + red[1][0] + red[2][0] + red[3][0];
            float Q = red[0][1] + red[1][1] + red[2][1] + red[3][1];
            float m = S * (1.f / Bsz);
            float var = Q * (1.f / Bsz) - m * m;
            P.m2[b] = m;
            P.r2[b] = rsqrtf(var + BN_EPS);
        }
    }
    grid.sync();

    // ---- Phase E: BN2 + row L2-normalize + write ----
    float y = 0.f;
    if (tid < OUTn) {
        float m = P.m2[tid], r = P.r2[tid];
        y = fmaf((yp_reg - m) * r, P.g2[tid], P.be2[tid]);
        float sq = y * y;
        #pragma unroll
        for (int off = 32; off > 0; off >>= 1) sq += __shfl_down(sq, off, 64);
        if (lane == 0) red[wave][0] = sq;   // waves 0 and 1
    }
    __syncthreads();
    if (tid < OUTn) {
        float total = red[0][0] + red[1][0];
        float norm  = fmaxf(sqrtf(total), 1e-12f);
        P.out[b * OUTn + tid] = y / norm;
    }
}

extern "C" void kernel_launch(void* const* d_in, const int* in_sizes, int n_in,
                              void* d_out, int out_size, void* d_ws, size_t ws_size,
                              hipStream_t stream) {
    Params P;
    P.pts0 = (const float*)d_in[0];
    P.cnt0 = (const int*)  d_in[1];
    P.pts1 = (const float*)d_in[2];
    P.cnt1 = (const int*)  d_in[3];
    P.c0   = (const float*)d_in[4];
    P.ls0  = (const float*)d_in[5];
    P.c1   = (const float*)d_in[6];
    P.ls1  = (const float*)d_in[7];
    P.W1   = (const float*)d_in[8];
    P.g1   = (const float*)d_in[9];
    P.be1  = (const float*)d_in[10];
    P.W2   = (const float*)d_in[11];
    P.g2   = (const float*)d_in[12];
    P.be2  = (const float*)d_in[13];
    P.out  = (float*)d_out;

    float* ws = (float*)d_ws;
    P.u    = ws;                 // 32768 floats
    P.ypre = ws + 32768;         // 32768 floats
    P.m1   = ws + 65536;         // 128
    P.r1   = P.m1 + 128;
    P.m2   = P.r1 + 128;
    P.r2   = P.m2 + 128;

    void* args[] = { (void*)&P };
    hipLaunchCooperativeKernel((const void*)fused, dim3(Bsz), dim3(512), args, 0, stream);
}

// Round 4
// 118.379 us; speedup vs baseline: 1.9563x; 1.9563x over previous
//
#include <hip/hip_runtime.h>

#define Bsz  256
#define Pn   2048
#define En   16
#define HIDn 128
#define OUTn 128
#define BN_EPS 1e-5f

// ---------------------------------------------------------------------------
// K1: per-batch SLayer (both homology dims, branch-free masked scan,
//     ln2-folded quadratic form) + x@W1 -> u.  grid = B x 512 threads.
// ---------------------------------------------------------------------------
__global__ __launch_bounds__(512) void k_slayer_w1(
    const float* __restrict__ pts0, const int* __restrict__ cnt0,
    const float* __restrict__ pts1, const int* __restrict__ cnt1,
    const float* __restrict__ c0, const float* __restrict__ ls0,
    const float* __restrict__ c1, const float* __restrict__ ls1,
    const float* __restrict__ W1,
    float* __restrict__ u)
{
    __shared__ float cst[2][En][5];
    __shared__ float red[8][32];
    __shared__ float xrow[32];

    const int tid = threadIdx.x;
    const int b   = blockIdx.x;

    // per-center constants: resp = exp2(a0*x^2 + a1*x + a2*y^2 + a3*y + a4)
    if (tid < 32) {
        int h = tid >> 4, e = tid & 15;
        const float* C = h ? c1 : c0;
        const float* L = h ? ls1 : ls0;
        float cx = C[e * 2 + 0], cy = C[e * 2 + 1];
        float z0 = L[e * 2 + 0], z1 = L[e * 2 + 1];
        float s0 = ((z0 > 20.f) ? z0 : logf(1.f + expf(z0))) + 1e-6f;
        float s1 = ((z1 > 20.f) ? z1 : logf(1.f + expf(z1))) + 1e-6f;
        const float L2E = 1.44269504088896340736f;
        float q0 = s0 * L2E, q1 = s1 * L2E;
        cst[h][e][0] = -q0;
        cst[h][e][1] = 2.f * q0 * cx;
        cst[h][e][2] = -q1;
        cst[h][e][3] = 2.f * q1 * cy;
        cst[h][e][4] = -(q0 * cx * cx + q1 * cy * cy);
    }
    __syncthreads();

    float acc[32];
    #pragma unroll
    for (int i = 0; i < 32; i++) acc[i] = 0.f;

    const int n0 = cnt0[b];
    const int n1 = cnt1[b];
    const float2* p0 = (const float2*)pts0 + (size_t)b * Pn;
    const float2* p1 = (const float2*)pts1 + (size_t)b * Pn;

    #pragma unroll
    for (int k = 0; k < 4; k++) {
        const int p = tid + k * 512;
        float2 a = p0[p];
        float2 c = p1[p];
        // mask: x -> 1e18 makes the exponent ~ -1e36 -> exp2 -> exactly 0
        float ax = (p < n0) ? a.x : 1e18f;
        float ay = (p < n0) ? a.y : 0.f;
        float cx = (p < n1) ? c.x : 1e18f;
        float cy = (p < n1) ? c.y : 0.f;
        float ax2 = ax * ax, ay2 = ay * ay;
        float cx2 = cx * cx, cy2 = cy * cy;
        #pragma unroll
        for (int e = 0; e < En; e++) {
            float t = cst[0][e][4];
            t = fmaf(cst[0][e][0], ax2, t);
            t = fmaf(cst[0][e][1], ax,  t);
            t = fmaf(cst[0][e][2], ay2, t);
            t = fmaf(cst[0][e][3], ay,  t);
            acc[e] += exp2f(t);
            float s = cst[1][e][4];
            s = fmaf(cst[1][e][0], cx2, s);
            s = fmaf(cst[1][e][1], cx,  s);
            s = fmaf(cst[1][e][2], cy2, s);
            s = fmaf(cst[1][e][3], cy,  s);
            acc[16 + e] += exp2f(s);
        }
    }

    // intra-wave butterfly, then cross-wave via LDS
    #pragma unroll
    for (int i = 0; i < 32; i++) {
        float v = acc[i];
        #pragma unroll
        for (int off = 32; off > 0; off >>= 1) v += __shfl_down(v, off, 64);
        acc[i] = v;
    }
    const int wave = tid >> 6, lane = tid & 63;
    if (lane == 0) {
        #pragma unroll
        for (int i = 0; i < 32; i++) red[wave][i] = acc[i];
    }
    __syncthreads();
    if (tid < 32) {
        float s = 0.f;
        #pragma unroll
        for (int w = 0; w < 8; w++) s += red[w][tid];
        xrow[tid] = s;
    }
    __syncthreads();

    // u[b,:] = xrow @ W1  (W1 [32,128] row-major; coalesced over tid)
    if (tid < HIDn) {
        float a = 0.f;
        #pragma unroll
        for (int k = 0; k < 32; k++) a = fmaf(xrow[k], W1[k * HIDn + tid], a);
        u[b * HIDn + tid] = a;
    }
}

// ---------------------------------------------------------------------------
// K2: BN1 (column stats recomputed from u — L2-served) + ReLU + h@W2 -> ypre
// grid = B x 128 threads
// ---------------------------------------------------------------------------
__global__ __launch_bounds__(128) void k_bn1_w2(
    const float* __restrict__ u, const float* __restrict__ W2,
    const float* __restrict__ g1, const float* __restrict__ be1,
    float* __restrict__ ypre)
{
    __shared__ float hrow[HIDn];
    const int j = threadIdx.x, b = blockIdx.x;

    float s = 0.f, sq = 0.f, uv = 0.f;
    #pragma unroll 8
    for (int bb = 0; bb < Bsz; bb++) {
        float v = u[bb * HIDn + j];
        s += v; sq = fmaf(v, v, sq);
        if (bb == b) uv = v;
    }
    float m    = s * (1.f / Bsz);
    float var  = sq * (1.f / Bsz) - m * m;
    float rstd = rsqrtf(var + BN_EPS);
    float h    = fmaxf((uv - m) * rstd * g1[j] + be1[j], 0.f);
    hrow[j] = h;
    __syncthreads();

    float a = 0.f;
    #pragma unroll 8
    for (int k = 0; k < HIDn; k++) a = fmaf(hrow[k], W2[k * OUTn + j], a);
    ypre[b * OUTn + j] = a;
}

// ---------------------------------------------------------------------------
// K3: BN2 (column stats recomputed from ypre) + row L2-normalize + write out
// grid = B x 128 threads
// ---------------------------------------------------------------------------
__global__ __launch_bounds__(128) void k_bn2_norm(
    const float* __restrict__ ypre,
    const float* __restrict__ g2, const float* __restrict__ be2,
    float* __restrict__ out)
{
    __shared__ float part[2];
    const int j = threadIdx.x, b = blockIdx.x;

    float s = 0.f, sq = 0.f, yv = 0.f;
    #pragma unroll 8
    for (int bb = 0; bb < Bsz; bb++) {
        float v = ypre[bb * OUTn + j];
        s += v; sq = fmaf(v, v, sq);
        if (bb == b) yv = v;
    }
    float m    = s * (1.f / Bsz);
    float var  = sq * (1.f / Bsz) - m * m;
    float rstd = rsqrtf(var + BN_EPS);
    float y    = (yv - m) * rstd * g2[j] + be2[j];

    float s2 = y * y;
    #pragma unroll
    for (int off = 32; off > 0; off >>= 1) s2 += __shfl_down(s2, off, 64);
    if ((j & 63) == 0) part[j >> 6] = s2;
    __syncthreads();
    float total = part[0] + part[1];
    float norm  = fmaxf(sqrtf(total), 1e-12f);
    out[b * OUTn + j] = y / norm;
}

extern "C" void kernel_launch(void* const* d_in, const int* in_sizes, int n_in,
                              void* d_out, int out_size, void* d_ws, size_t ws_size,
                              hipStream_t stream) {
    const float* pts0 = (const float*)d_in[0];
    const int*   cnt0 = (const int*)  d_in[1];
    const float* pts1 = (const float*)d_in[2];
    const int*   cnt1 = (const int*)  d_in[3];
    const float* c0   = (const float*)d_in[4];
    const float* ls0  = (const float*)d_in[5];
    const float* c1   = (const float*)d_in[6];
    const float* ls1  = (const float*)d_in[7];
    const float* W1   = (const float*)d_in[8];
    const float* g1   = (const float*)d_in[9];
    const float* be1  = (const float*)d_in[10];
    const float* W2   = (const float*)d_in[11];
    const float* g2   = (const float*)d_in[12];
    const float* be2  = (const float*)d_in[13];
    float* out = (float*)d_out;

    float* ws   = (float*)d_ws;
    float* u    = ws;              // B*HID = 32768 floats
    float* ypre = ws + 32768;      // B*OUT = 32768 floats

    k_slayer_w1<<<Bsz, 512, 0, stream>>>(pts0, cnt0, pts1, cnt1,
                                         c0, ls0, c1, ls1, W1, u);
    k_bn1_w2<<<Bsz, 128, 0, stream>>>(u, W2, g1, be1, ypre);
    k_bn2_norm<<<Bsz, 128, 0, stream>>>(ypre, g2, be2, out);
}